// Round 4
// baseline (295.203 us; speedup 1.0000x reference)
//
#include <hip/hip_runtime.h>
#include <hip/hip_bf16.h>

#define N_NODES 50000
#define N_RELS 8
#define IN_DIM 128
#define OUT_DIM 128
#define N_EDGES 800000
#define NR (N_NODES * N_RELS)              /* 400000 keys (tgt*8+rel) */
#define KDIM (N_RELS * IN_DIM)             /* 1024 = GEMM K */
#define SCAN_ELEMS 2048
#define SCAN_NBLK ((NR + SCAN_ELEMS - 1) / SCAN_ELEMS)  /* 196 */
#define M_PAD 50048                        /* 782 blocks * 64 rows */
#define CNT_BLKS ((N_EDGES / 4 + 255) / 256)   /* 782 */
#define CW_BLKS ((N_RELS * IN_DIM * OUT_DIM + 255) / 256) /* 512 */
#define FB_BLKS ((N_NODES * IN_DIM / 8 + 255) / 256)      /* 3125 */

typedef __attribute__((ext_vector_type(8))) short bf16x8;
typedef __attribute__((ext_vector_type(4))) float floatx4;
typedef __attribute__((ext_vector_type(4))) unsigned int uintx4;

__device__ inline unsigned short f2bf(float f) {
    unsigned u = __builtin_bit_cast(unsigned, f);
    u += 0x7fff + ((u >> 16) & 1);   // round-to-nearest-even
    return (unsigned short)(u >> 16);
}
__device__ inline float bflo(unsigned u) {   // low bf16 of a packed pair
    return __builtin_bit_cast(float, u << 16);
}
__device__ inline float bfhi(unsigned u) {   // high bf16 of a packed pair
    return __builtin_bit_cast(float, u & 0xffff0000u);
}

// ---------------- prep: histogram + W-conversion + feature-conversion ----------------
__global__ void prep_kernel(const int* __restrict__ tri, const float* __restrict__ W,
                            const float* __restrict__ features,
                            int* __restrict__ cnt, unsigned short* __restrict__ Wtf,
                            unsigned short* __restrict__ featB) {
    const int b = blockIdx.x;
    if (b < CNT_BLKS) {
        int t = b * 256 + threadIdx.x;
        if (t >= N_EDGES / 4) return;
        const int4* tri4 = (const int4*)tri;
        int4 a = tri4[3 * t], v = tri4[3 * t + 1], c = tri4[3 * t + 2];
        // edges: (a.x,a.y,a.z) (a.w,v.x,v.y) (v.z,v.w,c.x) (c.y,c.z,c.w)
        atomicAdd(&cnt[a.z * N_RELS + a.y], 1);
        atomicAdd(&cnt[v.y * N_RELS + v.x], 1);
        atomicAdd(&cnt[c.x * N_RELS + v.w], 1);
        atomicAdd(&cnt[c.w * N_RELS + c.z], 1);
    } else if (b < CNT_BLKS + CW_BLKS) {
        int idx = (b - CNT_BLKS) * 256 + threadIdx.x;   // 0 .. 131071
        if (idx >= N_RELS * IN_DIM * OUT_DIM) return;
        int e  = idx & 7;
        int l  = (idx >> 3) & 63;
        int ks = (idx >> 9) & 31;
        int nt = idx >> 14;
        int o = nt * 16 + (l & 15);
        int k = ks * 32 + (l >> 4) * 8 + e;             // global K index
        Wtf[idx] = f2bf(W[(k >> 7) * (IN_DIM * OUT_DIM) + (k & 127) * OUT_DIM + o]);
    } else {
        int t = (b - CNT_BLKS - CW_BLKS) * 256 + threadIdx.x;   // 8 floats each
        if (t >= N_NODES * IN_DIM / 8) return;
        const float4* f4 = (const float4*)features;
        float4 x = f4[2 * t], y = f4[2 * t + 1];
        uint4 o;
        o.x = (unsigned)f2bf(x.x) | ((unsigned)f2bf(x.y) << 16);
        o.y = (unsigned)f2bf(x.z) | ((unsigned)f2bf(x.w) << 16);
        o.z = (unsigned)f2bf(y.x) | ((unsigned)f2bf(y.y) << 16);
        o.w = (unsigned)f2bf(y.z) | ((unsigned)f2bf(y.w) << 16);
        ((uint4*)featB)[t] = o;
    }
}

// ---------------- 2-pass scan ----------------
__global__ void scan_part(const int* __restrict__ cnt, int* __restrict__ bsum) {
    __shared__ int s[256];
    int b = blockIdx.x, t = threadIdx.x;
    int base = b * SCAN_ELEMS + t * 8;
    int sum = 0;
#pragma unroll
    for (int k = 0; k < 8; ++k) {
        int i = base + k;
        sum += (i < NR) ? cnt[i] : 0;
    }
    s[t] = sum; __syncthreads();
    for (int off = 128; off > 0; off >>= 1) {
        if (t < off) s[t] += s[t + off];
        __syncthreads();
    }
    if (t == 0) bsum[b] = s[0];
}

__global__ __launch_bounds__(256) void scan_fused(
    const int* __restrict__ cnt, const int* __restrict__ bsum,
    int* __restrict__ segOff, int* __restrict__ cursor)
{
    __shared__ int s[256];
    __shared__ int sboff;
    const int b = blockIdx.x, t = threadIdx.x;

    // phase 1: scan the 196 per-block sums; this block's exclusive base
    int vb = (t < SCAN_NBLK) ? bsum[t] : 0;
    s[t] = vb; __syncthreads();
    for (int off = 1; off < 256; off <<= 1) {
        int x = (t >= off) ? s[t - off] : 0;
        __syncthreads();
        s[t] += x;
        __syncthreads();
    }
    if (t == 0) sboff = (b == 0) ? 0 : s[b - 1];
    __syncthreads();
    const int boff = sboff;

    // phase 2: per-element scan of this block's 2048 counters
    const int base = b * SCAN_ELEMS + t * 8;
    int v[8]; int sum = 0;
#pragma unroll
    for (int k = 0; k < 8; ++k) {
        int i = base + k;
        v[k] = (i < NR) ? cnt[i] : 0;
        sum += v[k];
    }
    s[t] = sum; __syncthreads();
    for (int off = 1; off < 256; off <<= 1) {
        int x = (t >= off) ? s[t - off] : 0;
        __syncthreads();
        s[t] += x;
        __syncthreads();
    }
    int run = boff + s[t] - sum;   // exclusive offset for this thread's chunk
#pragma unroll
    for (int k = 0; k < 8; ++k) {
        int i = base + k;
        if (i < NR) { segOff[i] = run; cursor[i] = run; run += v[k]; }
    }
    if (b == 0 && t == 0) segOff[NR] = N_EDGES;
}

// ---------------- scatter: 1 edge per thread ----------------
__global__ void scatter_kernel(const int* __restrict__ tri, int* __restrict__ cursor,
                               int* __restrict__ sortedSrc) {
    int e = blockIdx.x * 256 + threadIdx.x;
    if (e >= N_EDGES) return;
    int src = tri[3 * e];
    int rel = tri[3 * e + 1];
    int tgt = tri[3 * e + 2];
    int p = atomicAdd(&cursor[tgt * N_RELS + rel], 1);
    sortedSrc[p] = src;
}

// ---------------- phase A: per-node segment mean -> bf16 agg row ----------------
// R9: aggG written once/read once -> nontemporal store (evict-first) so the
// 102.5 MB stream stops thrashing featB out of L3. j-loop unrolled x2.
__global__ __launch_bounds__(256) void agg_kernel(
    const int* __restrict__ sortedSrc, const int* __restrict__ segOff,
    const unsigned short* __restrict__ featB, unsigned short* __restrict__ aggG)
{
    const int wave = threadIdx.x >> 6, lane = threadIdx.x & 63;
    const int node = blockIdx.x * 4 + wave;
    const int q = lane >> 4, l16 = lane & 15;

    int bnd = 0;
    if (lane < 9) bnd = segOff[node * N_RELS + lane];
    int s[9];
#pragma unroll
    for (int i = 0; i < 9; ++i) s[i] = __shfl(bnd, i);

    const int e0 = s[0], eN = s[8];
    int srcw = 0;
    if (e0 + lane < eN) srcw = sortedSrc[e0 + lane];   // window of 64 srcs

    const unsigned short* fb = featB + 8 * l16;        // dims 8*l16 .. 8*l16+7
    unsigned short* dst = aggG + (size_t)node * KDIM + 8 * l16;

#pragma unroll
    for (int p = 0; p < 2; ++p) {
        const int r = 4 * p + q;
        const int s0v = s[r], s1v = s[r + 1];
        const int len = s1v - s0v;
        int m0x = __shfl_xor(len, 16);                 // full exec
        int jm = (len > m0x) ? len : m0x;
        int m1x = __shfl_xor(jm, 32);                  // full exec
        const int jmax = (jm > m1x) ? jm : m1x;        // wave-uniform
        float a0 = 0.f, a1 = 0.f, a2 = 0.f, a3 = 0.f;
        float a4 = 0.f, a5 = 0.f, a6 = 0.f, a7 = 0.f;
        for (int j = 0; j < jmax; j += 2) {            // uniform trip count
            const int ea = s0v + j;
            const int ia = ea - e0;
            const int swina = __shfl(srcw, ia & 63);   // full exec, safe
            const int eb = ea + 1;
            const int ib = ia + 1;
            const int swinb = __shfl(srcw, ib & 63);   // full exec, safe
            const bool pa = j < len;
            const bool pb = j + 1 < len;
            int srca = 0, srcb = 0;
            if (pa) srca = (ia < 64) ? swina : sortedSrc[ea];
            if (pb) srcb = (ib < 64) ? swinb : sortedSrc[eb];
            // both gathers issued unconditionally (row 0 harmless, cached)
            uint4 ua = *(const uint4*)&fb[srca * IN_DIM];
            uint4 ub = *(const uint4*)&fb[srcb * IN_DIM];
            if (pa) {
                a0 += bflo(ua.x); a1 += bfhi(ua.x);
                a2 += bflo(ua.y); a3 += bfhi(ua.y);
                a4 += bflo(ua.z); a5 += bfhi(ua.z);
                a6 += bflo(ua.w); a7 += bfhi(ua.w);
            }
            if (pb) {
                a0 += bflo(ub.x); a1 += bfhi(ub.x);
                a2 += bflo(ub.y); a3 += bfhi(ub.y);
                a4 += bflo(ub.z); a5 += bfhi(ub.z);
                a6 += bflo(ub.w); a7 += bfhi(ub.w);
            }
        }
        const float inv = (len > 0) ? 1.0f / (float)len : 0.0f;
        uintx4 pk;
        pk[0] = (unsigned)f2bf(a0 * inv) | ((unsigned)f2bf(a1 * inv) << 16);
        pk[1] = (unsigned)f2bf(a2 * inv) | ((unsigned)f2bf(a3 * inv) << 16);
        pk[2] = (unsigned)f2bf(a4 * inv) | ((unsigned)f2bf(a5 * inv) << 16);
        pk[3] = (unsigned)f2bf(a6 * inv) | ((unsigned)f2bf(a7 * inv) << 16);
        __builtin_nontemporal_store(pk, (uintx4*)&dst[r * IN_DIM]);  // evict-first
    }
}

// ---------------- phase B: out[M_PAD x 128] = agg @ W + bias ----------------
// R12: barrier-free register-direct GEMM. R3's pipelined-LDS attempt showed
// the barrier/LDS structure itself is the stall (MfmaUtil 7.8%, all pipes
// idle). A-fragments load straight from global: lane reads 16 B at
// row = m0+wm*32+st*16+ln16, k = c*128+ksl*32+qk*8 -> wave covers 16 rows x
// 64 B contiguous segments. No LDS, no __syncthreads, no s_waitcnt games:
// waves fully independent, compiler pipelines chunks (unroll 2).
__global__ __launch_bounds__(256) void gemm_kernel(
    const unsigned short* __restrict__ aggG,
    const unsigned short* __restrict__ Wtf,
    const float* __restrict__ bias,
    float* __restrict__ out)
{
    const int tid = threadIdx.x;
    const int wave = tid >> 6, lane = tid & 63;
    const int qk = lane >> 4, ln16 = lane & 15;
    const int m0 = blockIdx.x * 64;
    const int wm = wave & 1, wn = wave >> 1;

    floatx4 acc[2][4];
#pragma unroll
    for (int st = 0; st < 2; ++st)
#pragma unroll
        for (int nt = 0; nt < 4; ++nt) acc[st][nt] = (floatx4){0.f, 0.f, 0.f, 0.f};

    // per-lane A base for st=0 / st=1 (rows 16 apart)
    const unsigned short* aBase0 =
        aggG + (size_t)(m0 + wm * 32 + ln16) * KDIM + qk * 8;
    const unsigned short* aBase1 = aBase0 + (size_t)16 * KDIM;

#pragma unroll 2
    for (int c = 0; c < 8; ++c) {
#pragma unroll
        for (int ksl = 0; ksl < 4; ++ksl) {
            const int off = c * 128 + ksl * 32;
            bf16x8 a0 = *(const bf16x8*)(aBase0 + off);
            bf16x8 a1 = *(const bf16x8*)(aBase1 + off);
            const int ks = c * 4 + ksl;
#pragma unroll
            for (int nt = 0; nt < 4; ++nt) {
                const int ntg = wn * 4 + nt;
                bf16x8 b = *(const bf16x8*)&Wtf[(size_t)((ntg * 32 + ks) * 64 + lane) * 8];
                acc[0][nt] = __builtin_amdgcn_mfma_f32_16x16x32_bf16(a0, b, acc[0][nt], 0, 0, 0);
                acc[1][nt] = __builtin_amdgcn_mfma_f32_16x16x32_bf16(a1, b, acc[1][nt], 0, 0, 0);
            }
        }
    }

    // D layout: col = lane&15, row = (lane>>4)*4 + reg
#pragma unroll
    for (int nt = 0; nt < 4; ++nt) {
        const int o = (wn * 4 + nt) * 16 + ln16;
        const float bv = bias[o];
#pragma unroll
        for (int st = 0; st < 2; ++st)
#pragma unroll
            for (int j = 0; j < 4; ++j) {
                const int t = m0 + wm * 32 + st * 16 + qk * 4 + j;
                if (t < N_NODES) out[(size_t)t * OUT_DIM + o] = acc[st][nt][j] + bv;
            }
    }
}

extern "C" void kernel_launch(void* const* d_in, const int* in_sizes, int n_in,
                              void* d_out, int out_size, void* d_ws, size_t ws_size,
                              hipStream_t stream)
{
    const int*   tri      = (const int*)d_in[0];
    const float* features = (const float*)d_in[1];
    const float* W        = (const float*)d_in[2];
    const float* bias     = (const float*)d_in[3];
    float* out = (float*)d_out;

    char* ws = (char*)d_ws;
    unsigned short* Wtf = (unsigned short*)ws; ws += (size_t)OUT_DIM * KDIM * 2;  // 256 KB
    int* cnt       = (int*)ws; ws += (size_t)NR * 4;
    int* segOff    = (int*)ws; ws += (size_t)(NR + 4) * 4;
    int* cursor    = (int*)ws; ws += (size_t)NR * 4;
    int* bsum      = (int*)ws; ws += (size_t)SCAN_NBLK * 4;
    int* sortedSrc = (int*)ws; ws += (size_t)N_EDGES * 4;
    unsigned short* featB = (unsigned short*)ws; ws += (size_t)N_NODES * IN_DIM * 2;  // 12.8 MB
    unsigned short* aggG  = (unsigned short*)ws; ws += (size_t)M_PAD * KDIM * 2;      // 102.5 MB
    (void)ws_size; (void)in_sizes; (void)n_in; (void)out_size;

    hipMemsetAsync(cnt, 0, NR * sizeof(int), stream);
    prep_kernel<<<CNT_BLKS + CW_BLKS + FB_BLKS, 256, 0, stream>>>(tri, W, features, cnt, Wtf, featB);
    scan_part<<<SCAN_NBLK, 256, 0, stream>>>(cnt, bsum);
    scan_fused<<<SCAN_NBLK, 256, 0, stream>>>(cnt, bsum, segOff, cursor);
    scatter_kernel<<<(N_EDGES + 255) / 256, 256, 0, stream>>>(tri, cursor, sortedSrc);
    agg_kernel<<<N_NODES / 4, 256, 0, stream>>>(sortedSrc, segOff, featB, aggG);
    gemm_kernel<<<M_PAD / 64, 256, 0, stream>>>(aggG, Wtf, bias, out);
}

// Round 5
// 259.692 us; speedup vs baseline: 1.1367x; 1.1367x over previous
//
#include <hip/hip_runtime.h>
#include <hip/hip_bf16.h>

#define N_NODES 50000
#define N_RELS 8
#define IN_DIM 128
#define OUT_DIM 128
#define N_EDGES 800000
#define NR (N_NODES * N_RELS)              /* 400000 keys (tgt*8+rel) */
#define KDIM (N_RELS * IN_DIM)             /* 1024 = GEMM K */
#define SCAN_ELEMS 2048
#define SCAN_NBLK ((NR + SCAN_ELEMS - 1) / SCAN_ELEMS)  /* 196 */
#define FUSE_BLKS 782                      /* 782 * 64 = 50048 >= N_NODES */
#define CNT_BLKS ((N_EDGES / 4 + 255) / 256)   /* 782 */
#define CW_BLKS ((N_RELS * IN_DIM * OUT_DIM + 255) / 256) /* 512 */
#define FB_BLKS ((N_NODES * IN_DIM / 8 + 255) / 256)      /* 3125 */

typedef __attribute__((ext_vector_type(8))) short bf16x8;
typedef __attribute__((ext_vector_type(4))) float floatx4;
typedef __attribute__((ext_vector_type(4))) unsigned int uintx4;

__device__ inline unsigned short f2bf(float f) {
    unsigned u = __builtin_bit_cast(unsigned, f);
    u += 0x7fff + ((u >> 16) & 1);   // round-to-nearest-even
    return (unsigned short)(u >> 16);
}
__device__ inline float bflo(unsigned u) {   // low bf16 of a packed pair
    return __builtin_bit_cast(float, u << 16);
}
__device__ inline float bfhi(unsigned u) {   // high bf16 of a packed pair
    return __builtin_bit_cast(float, u & 0xffff0000u);
}

// ---------------- prep: histogram + W-conversion + feature-conversion ----------------
__global__ void prep_kernel(const int* __restrict__ tri, const float* __restrict__ W,
                            const float* __restrict__ features,
                            int* __restrict__ cnt, unsigned short* __restrict__ Wtf,
                            unsigned short* __restrict__ featB) {
    const int b = blockIdx.x;
    if (b < CNT_BLKS) {
        int t = b * 256 + threadIdx.x;
        if (t >= N_EDGES / 4) return;
        const int4* tri4 = (const int4*)tri;
        int4 a = tri4[3 * t], v = tri4[3 * t + 1], c = tri4[3 * t + 2];
        // edges: (a.x,a.y,a.z) (a.w,v.x,v.y) (v.z,v.w,c.x) (c.y,c.z,c.w)
        atomicAdd(&cnt[a.z * N_RELS + a.y], 1);
        atomicAdd(&cnt[v.y * N_RELS + v.x], 1);
        atomicAdd(&cnt[c.x * N_RELS + v.w], 1);
        atomicAdd(&cnt[c.w * N_RELS + c.z], 1);
    } else if (b < CNT_BLKS + CW_BLKS) {
        int idx = (b - CNT_BLKS) * 256 + threadIdx.x;   // 0 .. 131071
        if (idx >= N_RELS * IN_DIM * OUT_DIM) return;
        int e  = idx & 7;
        int l  = (idx >> 3) & 63;
        int ks = (idx >> 9) & 31;
        int nt = idx >> 14;
        int o = nt * 16 + (l & 15);
        int k = ks * 32 + (l >> 4) * 8 + e;             // global K index
        Wtf[idx] = f2bf(W[(k >> 7) * (IN_DIM * OUT_DIM) + (k & 127) * OUT_DIM + o]);
    } else {
        int t = (b - CNT_BLKS - CW_BLKS) * 256 + threadIdx.x;   // 8 floats each
        if (t >= N_NODES * IN_DIM / 8) return;
        const float4* f4 = (const float4*)features;
        float4 x = f4[2 * t], y = f4[2 * t + 1];
        uint4 o;
        o.x = (unsigned)f2bf(x.x) | ((unsigned)f2bf(x.y) << 16);
        o.y = (unsigned)f2bf(x.z) | ((unsigned)f2bf(x.w) << 16);
        o.z = (unsigned)f2bf(y.x) | ((unsigned)f2bf(y.y) << 16);
        o.w = (unsigned)f2bf(y.z) | ((unsigned)f2bf(y.w) << 16);
        ((uint4*)featB)[t] = o;
    }
}

// ---------------- 2-pass scan ----------------
__global__ void scan_part(const int* __restrict__ cnt, int* __restrict__ bsum) {
    __shared__ int s[256];
    int b = blockIdx.x, t = threadIdx.x;
    int base = b * SCAN_ELEMS + t * 8;
    int sum = 0;
#pragma unroll
    for (int k = 0; k < 8; ++k) {
        int i = base + k;
        sum += (i < NR) ? cnt[i] : 0;
    }
    s[t] = sum; __syncthreads();
    for (int off = 128; off > 0; off >>= 1) {
        if (t < off) s[t] += s[t + off];
        __syncthreads();
    }
    if (t == 0) bsum[b] = s[0];
}

__global__ __launch_bounds__(256) void scan_fused(
    const int* __restrict__ cnt, const int* __restrict__ bsum,
    int* __restrict__ segOff, int* __restrict__ cursor)
{
    __shared__ int s[256];
    __shared__ int sboff;
    const int b = blockIdx.x, t = threadIdx.x;

    // phase 1: scan the 196 per-block sums; this block's exclusive base
    int vb = (t < SCAN_NBLK) ? bsum[t] : 0;
    s[t] = vb; __syncthreads();
    for (int off = 1; off < 256; off <<= 1) {
        int x = (t >= off) ? s[t - off] : 0;
        __syncthreads();
        s[t] += x;
        __syncthreads();
    }
    if (t == 0) sboff = (b == 0) ? 0 : s[b - 1];
    __syncthreads();
    const int boff = sboff;

    // phase 2: per-element scan of this block's 2048 counters
    const int base = b * SCAN_ELEMS + t * 8;
    int v[8]; int sum = 0;
#pragma unroll
    for (int k = 0; k < 8; ++k) {
        int i = base + k;
        v[k] = (i < NR) ? cnt[i] : 0;
        sum += v[k];
    }
    s[t] = sum; __syncthreads();
    for (int off = 1; off < 256; off <<= 1) {
        int x = (t >= off) ? s[t - off] : 0;
        __syncthreads();
        s[t] += x;
        __syncthreads();
    }
    int run = boff + s[t] - sum;   // exclusive offset for this thread's chunk
#pragma unroll
    for (int k = 0; k < 8; ++k) {
        int i = base + k;
        if (i < NR) { segOff[i] = run; cursor[i] = run; run += v[k]; }
    }
    if (b == 0 && t == 0) segOff[NR] = N_EDGES;
}

// ---------------- scatter: 1 edge per thread ----------------
__global__ void scatter_kernel(const int* __restrict__ tri, int* __restrict__ cursor,
                               int* __restrict__ sortedSrc) {
    int e = blockIdx.x * 256 + threadIdx.x;
    if (e >= N_EDGES) return;
    int src = tri[3 * e];
    int rel = tri[3 * e + 1];
    int tgt = tri[3 * e + 2];
    int p = atomicAdd(&cursor[tgt * N_RELS + rel], 1);
    sortedSrc[p] = src;
}

// ---------------- fused agg + GEMM ----------------
// R13: the aggG round-trip (102.5 MB write + re-read) WAS the bottleneck —
// whichever of agg/gemm lost the L3 to the other went HBM-bound. Fuse:
// block = 64 nodes, 8 waves. Per pass p (rels 4p..4p+3): each wave runs the
// proven agg inner loop for 8 nodes, writing each node's 4 rel-rows into a
// 64 KB LDS A-tile (row 1024 B = 64 16B-units, unit XOR-swizzled by row&15
// -> conflict-floor frag reads); barrier; 16 K-slices of MFMA vs L2-resident
// Wtf; barrier. acc persists across passes. 2 blocks/CU (LDS) = 16 waves/CU
// keeps gather latency-hiding ~= the old standalone agg.
__global__ __launch_bounds__(512, 4) void fused_kernel(
    const int* __restrict__ sortedSrc, const int* __restrict__ segOff,
    const unsigned short* __restrict__ featB,
    const unsigned short* __restrict__ Wtf,
    const float* __restrict__ bias,
    float* __restrict__ out)
{
    __shared__ unsigned short Atile[64 * 512];   // 64 KB, row stride 1024 B
    const int tid = threadIdx.x;
    const int wave = tid >> 6, lane = tid & 63;
    const int q = lane >> 4, l16 = lane & 15;    // quarter / lane-in-quarter
    const int m0 = blockIdx.x * 64;
    const int wm = wave & 1, wn = wave >> 1;     // 2 (M) x 4 (N) wave grid

    floatx4 acc[2][2];
#pragma unroll
    for (int st = 0; st < 2; ++st)
#pragma unroll
        for (int nt = 0; nt < 2; ++nt) acc[st][nt] = (floatx4){0.f, 0.f, 0.f, 0.f};

    const unsigned short* fb = featB + 8 * l16;  // dims 8*l16 .. 8*l16+7

#pragma unroll
    for (int p = 0; p < 2; ++p) {
        // ---- agg phase: 8 nodes per wave, quarter q handles rel 4p+q ----
        for (int i = 0; i < 8; ++i) {
            const int nl = wave * 8 + i;         // local row 0..63
            const int node = m0 + nl;
            if (node < N_NODES) {
                int bnd = 0;
                if (lane < 5) bnd = segOff[node * N_RELS + 4 * p + lane];
                int sg[5];
#pragma unroll
                for (int k = 0; k < 5; ++k) sg[k] = __shfl(bnd, k);

                const int e0 = sg[0], eN = sg[4];
                int srcw = 0;
                if (e0 + lane < eN) srcw = sortedSrc[e0 + lane];  // 64-src window

                const int s0v = sg[q], s1v = sg[q + 1];
                const int len = s1v - s0v;
                int m0x = __shfl_xor(len, 16);               // full exec
                int jm = (len > m0x) ? len : m0x;
                int m1x = __shfl_xor(jm, 32);                // full exec
                const int jmax = (jm > m1x) ? jm : m1x;      // wave-uniform
                float a0 = 0.f, a1 = 0.f, a2 = 0.f, a3 = 0.f;
                float a4 = 0.f, a5 = 0.f, a6 = 0.f, a7 = 0.f;
                for (int j = 0; j < jmax; j += 2) {          // uniform trips
                    const int ea = s0v + j;
                    const int ia = ea - e0;
                    const int swina = __shfl(srcw, ia & 63); // full exec
                    const int ib = ia + 1;
                    const int swinb = __shfl(srcw, ib & 63); // full exec
                    const bool pa = j < len;
                    const bool pb = j + 1 < len;
                    int srca = 0, srcb = 0;
                    if (pa) srca = (ia < 64) ? swina : sortedSrc[ea];
                    if (pb) srcb = (ib < 64) ? swinb : sortedSrc[ea + 1];
                    uint4 ua = *(const uint4*)&fb[srca * IN_DIM];
                    uint4 ub = *(const uint4*)&fb[srcb * IN_DIM];
                    if (pa) {
                        a0 += bflo(ua.x); a1 += bfhi(ua.x);
                        a2 += bflo(ua.y); a3 += bfhi(ua.y);
                        a4 += bflo(ua.z); a5 += bfhi(ua.z);
                        a6 += bflo(ua.w); a7 += bfhi(ua.w);
                    }
                    if (pb) {
                        a0 += bflo(ub.x); a1 += bfhi(ub.x);
                        a2 += bflo(ub.y); a3 += bfhi(ub.y);
                        a4 += bflo(ub.z); a5 += bfhi(ub.z);
                        a6 += bflo(ub.w); a7 += bfhi(ub.w);
                    }
                }
                const float inv = (len > 0) ? 1.0f / (float)len : 0.0f;
                uintx4 pk;
                pk[0] = (unsigned)f2bf(a0 * inv) | ((unsigned)f2bf(a1 * inv) << 16);
                pk[1] = (unsigned)f2bf(a2 * inv) | ((unsigned)f2bf(a3 * inv) << 16);
                pk[2] = (unsigned)f2bf(a4 * inv) | ((unsigned)f2bf(a5 * inv) << 16);
                pk[3] = (unsigned)f2bf(a6 * inv) | ((unsigned)f2bf(a7 * inv) << 16);
                // unit u = q*16+l16 holds cols u*8..u*8+7; XOR-swizzle by row
                const int us = (q * 16 + l16) ^ (nl & 15);
                *(uintx4*)&Atile[(nl * 64 + us) * 8] = pk;
            }
        }
        __syncthreads();                 // A-tile chunk visible

        // ---- GEMM phase: K-chunk p (512 cols), wave-tile 32x32 ----
#pragma unroll
        for (int ksl = 0; ksl < 16; ++ksl) {
            const int ks = p * 16 + ksl;             // global k-slice
            bf16x8 a[2];
#pragma unroll
            for (int st = 0; st < 2; ++st) {
                const int r = wm * 32 + st * 16 + l16;
                const int us = (ksl * 4 + q) ^ (r & 15);
                a[st] = *(const bf16x8*)&Atile[(r * 64 + us) * 8];
            }
#pragma unroll
            for (int nt = 0; nt < 2; ++nt) {
                const int ntg = wn * 2 + nt;
                bf16x8 b = *(const bf16x8*)&Wtf[(size_t)((ntg * 32 + ks) * 64 + lane) * 8];
                acc[0][nt] = __builtin_amdgcn_mfma_f32_16x16x32_bf16(a[0], b, acc[0][nt], 0, 0, 0);
                acc[1][nt] = __builtin_amdgcn_mfma_f32_16x16x32_bf16(a[1], b, acc[1][nt], 0, 0, 0);
            }
        }
        __syncthreads();                 // reads done before next pass writes
    }

    // epilogue — D layout: col = lane&15, row = (lane>>4)*4 + reg
#pragma unroll
    for (int nt = 0; nt < 2; ++nt) {
        const int o = (wn * 2 + nt) * 16 + l16;
        const float bv = bias[o];
#pragma unroll
        for (int st = 0; st < 2; ++st)
#pragma unroll
            for (int j = 0; j < 4; ++j) {
                const int t = m0 + wm * 32 + st * 16 + q * 4 + j;
                if (t < N_NODES)
                    __builtin_nontemporal_store(acc[st][nt][j] + bv,
                                                &out[(size_t)t * OUT_DIM + o]);
            }
    }
}

extern "C" void kernel_launch(void* const* d_in, const int* in_sizes, int n_in,
                              void* d_out, int out_size, void* d_ws, size_t ws_size,
                              hipStream_t stream)
{
    const int*   tri      = (const int*)d_in[0];
    const float* features = (const float*)d_in[1];
    const float* W        = (const float*)d_in[2];
    const float* bias     = (const float*)d_in[3];
    float* out = (float*)d_out;

    char* ws = (char*)d_ws;
    unsigned short* Wtf = (unsigned short*)ws; ws += (size_t)OUT_DIM * KDIM * 2;  // 256 KB
    int* cnt       = (int*)ws; ws += (size_t)NR * 4;
    int* segOff    = (int*)ws; ws += (size_t)(NR + 4) * 4;
    int* cursor    = (int*)ws; ws += (size_t)NR * 4;
    int* bsum      = (int*)ws; ws += (size_t)SCAN_NBLK * 4;
    int* sortedSrc = (int*)ws; ws += (size_t)N_EDGES * 4;
    unsigned short* featB = (unsigned short*)ws; ws += (size_t)N_NODES * IN_DIM * 2;  // 12.8 MB
    (void)ws_size; (void)in_sizes; (void)n_in; (void)out_size;

    hipMemsetAsync(cnt, 0, NR * sizeof(int), stream);
    prep_kernel<<<CNT_BLKS + CW_BLKS + FB_BLKS, 256, 0, stream>>>(tri, W, features, cnt, Wtf, featB);
    scan_part<<<SCAN_NBLK, 256, 0, stream>>>(cnt, bsum);
    scan_fused<<<SCAN_NBLK, 256, 0, stream>>>(cnt, bsum, segOff, cursor);
    scatter_kernel<<<(N_EDGES + 255) / 256, 256, 0, stream>>>(tri, cursor, sortedSrc);
    fused_kernel<<<FUSE_BLKS, 512, 0, stream>>>(sortedSrc, segOff, featB, Wtf, bias, out);
}

// Round 6
// 249.066 us; speedup vs baseline: 1.1852x; 1.0427x over previous
//
#include <hip/hip_runtime.h>
#include <hip/hip_bf16.h>

#define N_NODES 50000
#define N_RELS 8
#define IN_DIM 128
#define OUT_DIM 128
#define N_EDGES 800000
#define NR (N_NODES * N_RELS)              /* 400000 keys (tgt*8+rel) */
#define KDIM (N_RELS * IN_DIM)             /* 1024 = GEMM K */
#define SCAN_ELEMS 2048
#define SCAN_NBLK ((NR + SCAN_ELEMS - 1) / SCAN_ELEMS)  /* 196 */
#define FUSE_BLKS 1563                     /* 1563 * 32 = 50016 >= N_NODES */
#define CNT_BLKS ((N_EDGES / 4 + 255) / 256)   /* 782 */
#define CW_BLKS ((N_RELS * IN_DIM * OUT_DIM + 255) / 256) /* 512 */
#define FB_BLKS ((N_NODES * IN_DIM / 8 + 255) / 256)      /* 3125 */

typedef __attribute__((ext_vector_type(8))) short bf16x8;
typedef __attribute__((ext_vector_type(4))) float floatx4;
typedef __attribute__((ext_vector_type(4))) unsigned int uintx4;

__device__ inline unsigned short f2bf(float f) {
    unsigned u = __builtin_bit_cast(unsigned, f);
    u += 0x7fff + ((u >> 16) & 1);   // round-to-nearest-even
    return (unsigned short)(u >> 16);
}
__device__ inline float bflo(unsigned u) {   // low bf16 of a packed pair
    return __builtin_bit_cast(float, u << 16);
}
__device__ inline float bfhi(unsigned u) {   // high bf16 of a packed pair
    return __builtin_bit_cast(float, u & 0xffff0000u);
}

// ---------------- prep: histogram + W-conversion + feature-conversion ----------------
__global__ void prep_kernel(const int* __restrict__ tri, const float* __restrict__ W,
                            const float* __restrict__ features,
                            int* __restrict__ cnt, unsigned short* __restrict__ Wtf,
                            unsigned short* __restrict__ featB) {
    const int b = blockIdx.x;
    if (b < CNT_BLKS) {
        int t = b * 256 + threadIdx.x;
        if (t >= N_EDGES / 4) return;
        const int4* tri4 = (const int4*)tri;
        int4 a = tri4[3 * t], v = tri4[3 * t + 1], c = tri4[3 * t + 2];
        // edges: (a.x,a.y,a.z) (a.w,v.x,v.y) (v.z,v.w,c.x) (c.y,c.z,c.w)
        atomicAdd(&cnt[a.z * N_RELS + a.y], 1);
        atomicAdd(&cnt[v.y * N_RELS + v.x], 1);
        atomicAdd(&cnt[c.x * N_RELS + v.w], 1);
        atomicAdd(&cnt[c.w * N_RELS + c.z], 1);
    } else if (b < CNT_BLKS + CW_BLKS) {
        int idx = (b - CNT_BLKS) * 256 + threadIdx.x;   // 0 .. 131071
        if (idx >= N_RELS * IN_DIM * OUT_DIM) return;
        int e  = idx & 7;
        int l  = (idx >> 3) & 63;
        int ks = (idx >> 9) & 31;
        int nt = idx >> 14;
        int o = nt * 16 + (l & 15);
        int k = ks * 32 + (l >> 4) * 8 + e;             // global K index
        Wtf[idx] = f2bf(W[(k >> 7) * (IN_DIM * OUT_DIM) + (k & 127) * OUT_DIM + o]);
    } else {
        int t = (b - CNT_BLKS - CW_BLKS) * 256 + threadIdx.x;   // 8 floats each
        if (t >= N_NODES * IN_DIM / 8) return;
        const float4* f4 = (const float4*)features;
        float4 x = f4[2 * t], y = f4[2 * t + 1];
        uint4 o;
        o.x = (unsigned)f2bf(x.x) | ((unsigned)f2bf(x.y) << 16);
        o.y = (unsigned)f2bf(x.z) | ((unsigned)f2bf(x.w) << 16);
        o.z = (unsigned)f2bf(y.x) | ((unsigned)f2bf(y.y) << 16);
        o.w = (unsigned)f2bf(y.z) | ((unsigned)f2bf(y.w) << 16);
        ((uint4*)featB)[t] = o;
    }
}

// ---------------- 2-pass scan ----------------
__global__ void scan_part(const int* __restrict__ cnt, int* __restrict__ bsum) {
    __shared__ int s[256];
    int b = blockIdx.x, t = threadIdx.x;
    int base = b * SCAN_ELEMS + t * 8;
    int sum = 0;
#pragma unroll
    for (int k = 0; k < 8; ++k) {
        int i = base + k;
        sum += (i < NR) ? cnt[i] : 0;
    }
    s[t] = sum; __syncthreads();
    for (int off = 128; off > 0; off >>= 1) {
        if (t < off) s[t] += s[t + off];
        __syncthreads();
    }
    if (t == 0) bsum[b] = s[0];
}

__global__ __launch_bounds__(256) void scan_fused(
    const int* __restrict__ cnt, const int* __restrict__ bsum,
    int* __restrict__ segOff, int* __restrict__ cursor)
{
    __shared__ int s[256];
    __shared__ int sboff;
    const int b = blockIdx.x, t = threadIdx.x;

    // phase 1: scan the 196 per-block sums; this block's exclusive base
    int vb = (t < SCAN_NBLK) ? bsum[t] : 0;
    s[t] = vb; __syncthreads();
    for (int off = 1; off < 256; off <<= 1) {
        int x = (t >= off) ? s[t - off] : 0;
        __syncthreads();
        s[t] += x;
        __syncthreads();
    }
    if (t == 0) sboff = (b == 0) ? 0 : s[b - 1];
    __syncthreads();
    const int boff = sboff;

    // phase 2: per-element scan of this block's 2048 counters
    const int base = b * SCAN_ELEMS + t * 8;
    int v[8]; int sum = 0;
#pragma unroll
    for (int k = 0; k < 8; ++k) {
        int i = base + k;
        v[k] = (i < NR) ? cnt[i] : 0;
        sum += v[k];
    }
    s[t] = sum; __syncthreads();
    for (int off = 1; off < 256; off <<= 1) {
        int x = (t >= off) ? s[t - off] : 0;
        __syncthreads();
        s[t] += x;
        __syncthreads();
    }
    int run = boff + s[t] - sum;   // exclusive offset for this thread's chunk
#pragma unroll
    for (int k = 0; k < 8; ++k) {
        int i = base + k;
        if (i < NR) { segOff[i] = run; cursor[i] = run; run += v[k]; }
    }
    if (b == 0 && t == 0) segOff[NR] = N_EDGES;
}

// ---------------- scatter: 1 edge per thread ----------------
__global__ void scatter_kernel(const int* __restrict__ tri, int* __restrict__ cursor,
                               int* __restrict__ sortedSrc) {
    int e = blockIdx.x * 256 + threadIdx.x;
    if (e >= N_EDGES) return;
    int src = tri[3 * e];
    int rel = tri[3 * e + 1];
    int tgt = tri[3 * e + 2];
    int p = atomicAdd(&cursor[tgt * N_RELS + rel], 1);
    sortedSrc[p] = src;
}

// ---------------- fused agg + GEMM ----------------
// R13: fusing killed the 205 MB aggG round-trip (fused 94.5 vs split ~105).
// R14: round-5 counters showed the cost: 64 KB A-tile -> 2 blocks/CU,
// occupancy 31%, VALUBusy 33% (vs 52% in the standalone agg) -> gather is
// latency-stalled behind barriers with nothing co-resident to overlap.
// Geometry change only, inner loops identical: M=32 rows/block (grid 1563),
// A-tile 32 KB -> 4 blocks/CU (32 waves, 100%). Each wave aggregates 4
// nodes/pass; GEMM wave-tile 16x32 (r = wm*16+l16, acc[2]).
__global__ __launch_bounds__(512, 8) void fused_kernel(
    const int* __restrict__ sortedSrc, const int* __restrict__ segOff,
    const unsigned short* __restrict__ featB,
    const unsigned short* __restrict__ Wtf,
    const float* __restrict__ bias,
    float* __restrict__ out)
{
    __shared__ unsigned short Atile[32 * 512];   // 32 KB, row stride 1024 B
    const int tid = threadIdx.x;
    const int wave = tid >> 6, lane = tid & 63;
    const int q = lane >> 4, l16 = lane & 15;    // quarter / lane-in-quarter
    const int m0 = blockIdx.x * 32;
    const int wm = wave & 1, wn = wave >> 1;     // 2 (M) x 4 (N) wave grid

    floatx4 acc[2];
#pragma unroll
    for (int nt = 0; nt < 2; ++nt) acc[nt] = (floatx4){0.f, 0.f, 0.f, 0.f};

    const unsigned short* fb = featB + 8 * l16;  // dims 8*l16 .. 8*l16+7

#pragma unroll
    for (int p = 0; p < 2; ++p) {
        // ---- agg phase: 4 nodes per wave, quarter q handles rel 4p+q ----
        for (int i = 0; i < 4; ++i) {
            const int nl = wave * 4 + i;         // local row 0..31
            const int node = m0 + nl;
            if (node < N_NODES) {
                int bnd = 0;
                if (lane < 5) bnd = segOff[node * N_RELS + 4 * p + lane];
                int sg[5];
#pragma unroll
                for (int k = 0; k < 5; ++k) sg[k] = __shfl(bnd, k);

                const int e0 = sg[0], eN = sg[4];
                int srcw = 0;
                if (e0 + lane < eN) srcw = sortedSrc[e0 + lane];  // 64-src window

                const int s0v = sg[q], s1v = sg[q + 1];
                const int len = s1v - s0v;
                int m0x = __shfl_xor(len, 16);               // full exec
                int jm = (len > m0x) ? len : m0x;
                int m1x = __shfl_xor(jm, 32);                // full exec
                const int jmax = (jm > m1x) ? jm : m1x;      // wave-uniform
                float a0 = 0.f, a1 = 0.f, a2 = 0.f, a3 = 0.f;
                float a4 = 0.f, a5 = 0.f, a6 = 0.f, a7 = 0.f;
                for (int j = 0; j < jmax; j += 2) {          // uniform trips
                    const int ea = s0v + j;
                    const int ia = ea - e0;
                    const int swina = __shfl(srcw, ia & 63); // full exec
                    const int ib = ia + 1;
                    const int swinb = __shfl(srcw, ib & 63); // full exec
                    const bool pa = j < len;
                    const bool pb = j + 1 < len;
                    int srca = 0, srcb = 0;
                    if (pa) srca = (ia < 64) ? swina : sortedSrc[ea];
                    if (pb) srcb = (ib < 64) ? swinb : sortedSrc[ea + 1];
                    uint4 ua = *(const uint4*)&fb[srca * IN_DIM];
                    uint4 ub = *(const uint4*)&fb[srcb * IN_DIM];
                    if (pa) {
                        a0 += bflo(ua.x); a1 += bfhi(ua.x);
                        a2 += bflo(ua.y); a3 += bfhi(ua.y);
                        a4 += bflo(ua.z); a5 += bfhi(ua.z);
                        a6 += bflo(ua.w); a7 += bfhi(ua.w);
                    }
                    if (pb) {
                        a0 += bflo(ub.x); a1 += bfhi(ub.x);
                        a2 += bflo(ub.y); a3 += bfhi(ub.y);
                        a4 += bflo(ub.z); a5 += bfhi(ub.z);
                        a6 += bflo(ub.w); a7 += bfhi(ub.w);
                    }
                }
                const float inv = (len > 0) ? 1.0f / (float)len : 0.0f;
                uintx4 pk;
                pk[0] = (unsigned)f2bf(a0 * inv) | ((unsigned)f2bf(a1 * inv) << 16);
                pk[1] = (unsigned)f2bf(a2 * inv) | ((unsigned)f2bf(a3 * inv) << 16);
                pk[2] = (unsigned)f2bf(a4 * inv) | ((unsigned)f2bf(a5 * inv) << 16);
                pk[3] = (unsigned)f2bf(a6 * inv) | ((unsigned)f2bf(a7 * inv) << 16);
                // unit u = q*16+l16 holds cols u*8..u*8+7; XOR-swizzle by row
                const int us = (q * 16 + l16) ^ (nl & 15);
                *(uintx4*)&Atile[(nl * 64 + us) * 8] = pk;
            }
        }
        __syncthreads();                 // A-tile chunk visible

        // ---- GEMM phase: K-chunk p (512 cols), wave-tile 16x32 ----
#pragma unroll
        for (int ksl = 0; ksl < 16; ++ksl) {
            const int ks = p * 16 + ksl;             // global k-slice
            const int r = wm * 16 + l16;
            const int us = (ksl * 4 + q) ^ (r & 15);
            bf16x8 a = *(const bf16x8*)&Atile[(r * 64 + us) * 8];
#pragma unroll
            for (int nt = 0; nt < 2; ++nt) {
                const int ntg = wn * 2 + nt;
                bf16x8 b = *(const bf16x8*)&Wtf[(size_t)((ntg * 32 + ks) * 64 + lane) * 8];
                acc[nt] = __builtin_amdgcn_mfma_f32_16x16x32_bf16(a, b, acc[nt], 0, 0, 0);
            }
        }
        __syncthreads();                 // reads done before next pass writes
    }

    // epilogue — D layout: col = lane&15, row = (lane>>4)*4 + reg
#pragma unroll
    for (int nt = 0; nt < 2; ++nt) {
        const int o = (wn * 2 + nt) * 16 + l16;
        const float bv = bias[o];
#pragma unroll
        for (int j = 0; j < 4; ++j) {
            const int t = m0 + wm * 16 + q * 4 + j;
            if (t < N_NODES)
                __builtin_nontemporal_store(acc[nt][j] + bv,
                                            &out[(size_t)t * OUT_DIM + o]);
        }
    }
}

extern "C" void kernel_launch(void* const* d_in, const int* in_sizes, int n_in,
                              void* d_out, int out_size, void* d_ws, size_t ws_size,
                              hipStream_t stream)
{
    const int*   tri      = (const int*)d_in[0];
    const float* features = (const float*)d_in[1];
    const float* W        = (const float*)d_in[2];
    const float* bias     = (const float*)d_in[3];
    float* out = (float*)d_out;

    char* ws = (char*)d_ws;
    unsigned short* Wtf = (unsigned short*)ws; ws += (size_t)OUT_DIM * KDIM * 2;  // 256 KB
    int* cnt       = (int*)ws; ws += (size_t)NR * 4;
    int* segOff    = (int*)ws; ws += (size_t)(NR + 4) * 4;
    int* cursor    = (int*)ws; ws += (size_t)NR * 4;
    int* bsum      = (int*)ws; ws += (size_t)SCAN_NBLK * 4;
    int* sortedSrc = (int*)ws; ws += (size_t)N_EDGES * 4;
    unsigned short* featB = (unsigned short*)ws; ws += (size_t)N_NODES * IN_DIM * 2;  // 12.8 MB
    (void)ws_size; (void)in_sizes; (void)n_in; (void)out_size;

    hipMemsetAsync(cnt, 0, NR * sizeof(int), stream);
    prep_kernel<<<CNT_BLKS + CW_BLKS + FB_BLKS, 256, 0, stream>>>(tri, W, features, cnt, Wtf, featB);
    scan_part<<<SCAN_NBLK, 256, 0, stream>>>(cnt, bsum);
    scan_fused<<<SCAN_NBLK, 256, 0, stream>>>(cnt, bsum, segOff, cursor);
    scatter_kernel<<<(N_EDGES + 255) / 256, 256, 0, stream>>>(tri, cursor, sortedSrc);
    fused_kernel<<<FUSE_BLKS, 512, 0, stream>>>(sortedSrc, segOff, featB, Wtf, bias, out);
}